// Round 17
// baseline (281.917 us; speedup 1.0000x reference)
//
#include <hip/hip_runtime.h>

#define B 8
#define C 256
#define NN 4096

typedef float f32x4 __attribute__((ext_vector_type(4)));
typedef short s16x8 __attribute__((ext_vector_type(8)));
typedef unsigned short u16;
typedef unsigned int u32;

__device__ __forceinline__ u16 f2bf(float f) {
    u32 u = __builtin_bit_cast(u32, f);
    u32 r = (u + 0x7fffu + ((u >> 16) & 1u)) >> 16;
    return (u16)r;
}
__device__ __forceinline__ float bf2f(u16 h) {
    u32 u = ((u32)h) << 16;
    return __builtin_bit_cast(float, u);
}

// LDS-only barrier: waits lgkmcnt(0) (LDS) but NOT vmcnt (outstanding global
// stores keep draining in background). Fused single asm block (round-14).
__device__ __forceinline__ void bar_lds() {
    asm volatile("s_waitcnt lgkmcnt(0)\n\ts_barrier" ::: "memory");
}

#define MFMA(a, b, c) __builtin_amdgcn_mfma_f32_16x16x32_bf16((a), (b), (c), 0, 0, 0)

// Validated convention (round-3 k_st1/k_st2 on-device): afrag@(lan,g)=A[lan][g*8+e],
// bfrag@(lan,g)=B[lan][g*8+e], D[r]@(lan,g) = sum A[g*4+r][:]*B[lan][:].
// Transposed-score: A = Q (rows n), B = K (rows m) -> lane holds m = mbase+lan,
// 4 consecutive n = g*4+r. Used IDENTICALLY in k_zsum and k_attn2.
__device__ __forceinline__ f32x4 score_mfma_t(s16x8 aqh, s16x8 aql, s16x8 bkh, s16x8 bkl) {
    f32x4 s = {0.f, 0.f, 0.f, 0.f};
    s = MFMA(aqh, bkl, s);
    s = MFMA(aql, bkh, s);
    s = MFMA(aqh, bkh, s);
    return s;
}

__global__ void k_sentinel(float* __restrict__ out, float v) { out[0] = v; }

// ---- weight casts into FRAGMENT-MAJOR layout: [(es*8+ck)*4+g][lan][8] ----
__global__ void k_cast(const float* __restrict__ wv, const float* __restrict__ wq,
                       const float* __restrict__ wk, u16* __restrict__ wvb,
                       u16* __restrict__ wqh, u16* __restrict__ wql,
                       u16* __restrict__ wkh, u16* __restrict__ wkl) {
    int i = blockIdx.x * 256 + threadIdx.x; // 320 blocks -> 81920
    if (i < 65536) {
        int e = i & 7, lan = (i >> 3) & 15, g = (i >> 7) & 3, ck = (i >> 9) & 7, es = i >> 12;
        wvb[i] = f2bf(wv[(es * 16 + lan) * 256 + ck * 32 + g * 8 + e]);
    } else if (i < 73728) {
        int j = i - 65536;
        int e = j & 7, lan = (j >> 3) & 15, g = (j >> 7) & 3, ck = (j >> 9) & 7, es = j >> 12;
        float v = wq[(es * 16 + lan) * 256 + ck * 32 + g * 8 + e];
        u16 h = f2bf(v); wqh[j] = h; wql[j] = f2bf(v - bf2f(h));
    } else {
        int j = i - 73728;
        int e = j & 7, lan = (j >> 3) & 15, g = (j >> 7) & 3, ck = (j >> 9) & 7, es = j >> 12;
        float v = wk[(es * 16 + lan) * 256 + ck * 32 + g * 8 + e];
        u16 h = f2bf(v); wkh[j] = h; wkl[j] = f2bf(v - bf2f(h));
    }
}

// ------- fused q/k/v projection: one xT staging (hi/lo), MFMA for all three -------
__global__ __launch_bounds__(256) void k_proj(
    const float* __restrict__ x,
    const u16* __restrict__ wvb, const float* __restrict__ bv,
    const u16* __restrict__ wqh, const u16* __restrict__ wql, const float* __restrict__ bq,
    const u16* __restrict__ wkh, const u16* __restrict__ wkl, const float* __restrict__ bk,
    u16* __restrict__ vbf,
    u16* __restrict__ qh, u16* __restrict__ ql, u16* __restrict__ kh, u16* __restrict__ kl)
{
    __shared__ u16 smh[64 * 264]; // xT hi [64 n][264 c-pad]
    __shared__ u16 sml[64 * 264]; // xT lo; reused later as sqk [64 n][136]
    int t = threadIdx.x;
    int w = t >> 6, l = t & 63;
    int lan = l & 15, g = l >> 4;
    int b = blockIdx.x, nblk = blockIdx.y;
    int n0 = nblk * 64;
#pragma unroll
    for (int p = 0; p < 16; p++) {
        int flat4 = t + p * 256;
        int c = flat4 >> 4, n4 = (flat4 & 15) * 4;
        float4 xv = *(const float4*)&x[((size_t)b * C + c) * NN + n0 + n4];
        float vv[4] = {xv.x, xv.y, xv.z, xv.w};
#pragma unroll
        for (int j = 0; j < 4; j++) {
            u16 h = f2bf(vv[j]);
            smh[(n4 + j) * 264 + c] = h;
            sml[(n4 + j) * 264 + c] = f2bf(vv[j] - bf2f(h));
        }
    }
    __syncthreads();
    f32x4 accv[16];
    f32x4 accq[2], acck[2];
#pragma unroll
    for (int es = 0; es < 16; es++) accv[es] = {0.f, 0.f, 0.f, 0.f};
#pragma unroll
    for (int es = 0; es < 2; es++) { accq[es] = {0.f, 0.f, 0.f, 0.f}; acck[es] = {0.f, 0.f, 0.f, 0.f}; }
    int nrow = w * 16 + lan;
    for (int ck = 0; ck < 8; ck++) {
        int c0 = ck * 32 + g * 8;
        int fb = ((ck * 4 + g) * 16 + lan) * 8; // fragment base (es stride 4096)
        s16x8 bh = *(const s16x8*)&smh[nrow * 264 + c0];
        s16x8 bl = *(const s16x8*)&sml[nrow * 264 + c0];
#pragma unroll
        for (int es = 0; es < 16; es++) {
            s16x8 afrag = *(const s16x8*)&wvb[es * 4096 + fb];
            accv[es] = MFMA(afrag, bh, accv[es]);
        }
#pragma unroll
        for (int es = 0; es < 2; es++) {
            s16x8 ah = *(const s16x8*)&wqh[es * 4096 + fb];
            s16x8 al = *(const s16x8*)&wql[es * 4096 + fb];
            accq[es] = MFMA(ah, bl, accq[es]);
            accq[es] = MFMA(al, bh, accq[es]);
            accq[es] = MFMA(ah, bh, accq[es]);
            ah = *(const s16x8*)&wkh[es * 4096 + fb];
            al = *(const s16x8*)&wkl[es * 4096 + fb];
            acck[es] = MFMA(ah, bl, acck[es]);
            acck[es] = MFMA(al, bh, acck[es]);
            acck[es] = MFMA(ah, bh, acck[es]);
        }
    }
    // V writeout
    int ncol = n0 + w * 16 + lan;
#pragma unroll
    for (int es = 0; es < 16; es++)
#pragma unroll
        for (int r = 0; r < 4; r++) {
            int e = es * 16 + g * 4 + r;
            vbf[((size_t)b * C + e) * NN + ncol] = f2bf(accv[es][r] + bv[e]);
        }
    // q/k: split hi/lo in-register, transpose via LDS (reuse sml as sqk[64][136]).
    bar_lds(); // don't drain the V stores above
    u16* sqk = sml;
    int nloc = w * 16 + lan;
#pragma unroll
    for (int es = 0; es < 2; es++)
#pragma unroll
        for (int r = 0; r < 4; r++) {
            int d = es * 16 + g * 4 + r;
            float qv = accq[es][r] + bq[d];
            float kv = acck[es][r] + bk[d];
            u16 qhi = f2bf(qv); u16 qlo = f2bf(qv - bf2f(qhi));
            u16 khi = f2bf(kv); u16 klo = f2bf(kv - bf2f(khi));
            sqk[nloc * 136 + 0 * 32 + d] = qhi;
            sqk[nloc * 136 + 1 * 32 + d] = qlo;
            sqk[nloc * 136 + 2 * 32 + d] = khi;
            sqk[nloc * 136 + 3 * 32 + d] = klo;
        }
    bar_lds();
    {
        int n = t >> 2, arr = t & 3;
        const u16* src = &sqk[n * 136 + arr * 32];
        u16* dst = (arr == 0 ? qh : arr == 1 ? ql : arr == 2 ? kh : kl) + ((size_t)b * NN + n0 + n) * 32;
        uint4 v0 = *(const uint4*)&src[0];
        uint4 v1 = *(const uint4*)&src[8];
        uint4 v2 = *(const uint4*)&src[16];
        uint4 v3 = *(const uint4*)&src[24];
        *(uint4*)&dst[0]  = v0;
        *(uint4*)&dst[8]  = v1;
        *(uint4*)&dst[16] = v2;
        *(uint4*)&dst[24] = v3;
    }
}

// ------- phase 1: Z sums, transposed scores (lane-local m rows) -------
__global__ __launch_bounds__(256) void k_zsum(
    const u16* __restrict__ qh, const u16* __restrict__ ql,
    const u16* __restrict__ kh, const u16* __restrict__ kl,
    float* __restrict__ zinv)
{
    __shared__ float lZ[4][64];
    int t = threadIdx.x;
    int w = t >> 6, l = t & 63;
    int lan = l & 15, g = l >> 4;
    int b = blockIdx.x, mblk = blockIdx.y;
    int m0 = mblk * 64;

    s16x8 bkh[4], bkl[4];
#pragma unroll
    for (int ms = 0; ms < 4; ms++) {
        size_t ko = ((size_t)b * NN + m0 + ms * 16 + lan) * 32 + g * 8;
        bkh[ms] = *(const s16x8*)&kh[ko];
        bkl[ms] = *(const s16x8*)&kl[ko];
    }
    float zacc[4] = {0.f, 0.f, 0.f, 0.f};
    for (int ci = 0; ci < 64; ci++) {
        int nt = ci * 4 + w;
        size_t qo = ((size_t)b * NN + nt * 16 + lan) * 32 + g * 8;
        s16x8 aqh = *(const s16x8*)&qh[qo];
        s16x8 aql = *(const s16x8*)&ql[qo];
#pragma unroll
        for (int ms = 0; ms < 4; ms++) {
            f32x4 s = score_mfma_t(aqh, aql, bkh[ms], bkl[ms]);
            zacc[ms] += __expf(s[0]) + __expf(s[1]) + __expf(s[2]) + __expf(s[3]);
        }
    }
#pragma unroll
    for (int ms = 0; ms < 4; ms++) {
        float v = zacc[ms];
        v += __shfl_xor(v, 16);
        v += __shfl_xor(v, 32);
        zacc[ms] = v;
    }
    if (g == 0) {
#pragma unroll
        for (int ms = 0; ms < 4; ms++) lZ[w][ms * 16 + lan] = zacc[ms];
    }
    __syncthreads();
    if (t < 64) {
        float Z = lZ[0][t] + lZ[1][t] + lZ[2][t] + lZ[3][t];
        zinv[(size_t)b * NN + m0 + t] = 1.0f / Z;
    }
}

// ------- phase 2: V in LDS (T14), bf16 A tile for PV only, DIRECT fp32 amap
//         stores from score registers (safe: lgkm barriers never drain stores;
//         adjacent waves complete each 128B line between the same barriers) -------
__global__ __launch_bounds__(256) void k_attn2(
    const float* __restrict__ x,
    const u16* __restrict__ qh, const u16* __restrict__ ql,
    const u16* __restrict__ kh, const u16* __restrict__ kl,
    const u16* __restrict__ vbf, const float* __restrict__ zinv,
    const float* __restrict__ gamma,
    float* __restrict__ out, float* __restrict__ amap)
{
    __shared__ u16 smv[16384];   // V tile [256 c][64 m], chunk-XOR-swizzled (32KB)
    __shared__ u16 mn[64 * 68];  // A tile [64 m][68-pad n] bf16, PV-only (8.7KB)
    int t = threadIdx.x;
    int w = t >> 6, l = t & 63;
    int lan = l & 15, g = l >> 4;
    int b = blockIdx.x, nblk = blockIdx.y;
    int n0 = nblk * 64;
    int nw = n0 + w * 16;

    size_t qo = ((size_t)b * NN + nw + lan) * 32 + g * 8;
    s16x8 aqh = *(const s16x8*)&qh[qo];
    s16x8 aql = *(const s16x8*)&ql[qo];

    f32x4 acc[16];
#pragma unroll
    for (int cs = 0; cs < 16; cs++) acc[cs] = {0.f, 0.f, 0.f, 0.f};
    const u16* vb = vbf + (size_t)b * C * NN;
    const float* ziv = zinv + (size_t)b * NN;
    float* amp = amap + (size_t)b * NN * NN;

    // prologue: stage V tile 0
    s16x8 vreg[8];
#pragma unroll
    for (int p = 0; p < 8; p++) {
        int f8 = t + p * 256; int c = f8 >> 3, j = f8 & 7;
        vreg[p] = *(const s16x8*)&vb[(size_t)c * NN + j * 8];
    }
#pragma unroll
    for (int p = 0; p < 8; p++) {
        int f8 = t + p * 256; int c = f8 >> 3, j = f8 & 7;
        *(s16x8*)&smv[c * 64 + ((j ^ (c & 7)) * 8)] = vreg[p];
    }
    bar_lds();

    for (int mstep = 0; mstep < 64; mstep++) {
        int m0 = mstep * 64;
        // scores: lane owns m = m0+ms*16+lan, n = nw+g*4+r.
        // amap row-slice (4 consecutive n) stored DIRECTLY from registers (fp32);
        // bf16 copy into mn only for PV.
#pragma unroll
        for (int ms = 0; ms < 4; ms++) {
            size_t ko = ((size_t)b * NN + m0 + ms * 16 + lan) * 32 + g * 8;
            s16x8 fkh = *(const s16x8*)&kh[ko];
            s16x8 fkl = *(const s16x8*)&kl[ko];
            f32x4 s = score_mfma_t(aqh, aql, fkh, fkl);
            float zi = ziv[m0 + ms * 16 + lan];
            f32x4 av;
#pragma unroll
            for (int r = 0; r < 4; r++) av[r] = __expf(s[r]) * zi;
            __builtin_nontemporal_store(av,
                (f32x4*)&amp[(size_t)(m0 + ms * 16 + lan) * NN + nw + g * 4]);
            uint2 pk;
            pk.x = (u32)f2bf(av[0]) | ((u32)f2bf(av[1]) << 16);
            pk.y = (u32)f2bf(av[2]) | ((u32)f2bf(av[3]) << 16);
            *(uint2*)&mn[(ms * 16 + lan) * 68 + w * 16 + g * 4] = pk;
        }
        bar_lds(); // bar1: mn visible to all waves (global stores NOT drained)
        // T14: issue next V tile's loads
        if (mstep < 63) {
#pragma unroll
            for (int p = 0; p < 8; p++) {
                int f8 = t + p * 256; int c = f8 >> 3, j = f8 & 7;
                vreg[p] = *(const s16x8*)&vb[(size_t)c * NN + m0 + 64 + j * 8];
            }
        }
        // PV: acc[cs] (c = cs*16+g*4+r, n = nw+lan) += V[c][m] * A[m][n]
#pragma unroll
        for (int ks = 0; ks < 2; ks++) {
            s16x8 bfrag;
#pragma unroll
            for (int e = 0; e < 8; e++)
                bfrag[e] = (short)mn[(ks * 32 + g * 8 + e) * 68 + w * 16 + lan];
#pragma unroll
            for (int cs = 0; cs < 16; cs++) {
                int row = cs * 16 + lan;
                s16x8 afrag = *(const s16x8*)&smv[row * 64 + (((ks * 4 + g) ^ (lan & 7)) * 8)];
                acc[cs] = MFMA(afrag, bfrag, acc[cs]);
            }
        }
        bar_lds(); // bar2: all reads of mn & smv complete
        if (mstep < 63) {
#pragma unroll
            for (int p = 0; p < 8; p++) {
                int f8 = t + p * 256; int c = f8 >> 3, j = f8 & 7;
                *(s16x8*)&smv[c * 64 + ((j ^ (c & 7)) * 8)] = vreg[p];
            }
        }
    }
    float gm = gamma[0];
    int ncol = nw + lan;
#pragma unroll
    for (int cs = 0; cs < 16; cs++)
#pragma unroll
        for (int r = 0; r < 4; r++) {
            int c = cs * 16 + g * 4 + r;
            size_t oi = ((size_t)b * C + c) * NN + ncol;
            out[oi] = gm * acc[cs][r] + x[oi];
        }
}

extern "C" void kernel_launch(void* const* d_in, const int* in_sizes, int n_in,
                              void* d_out, int out_size, void* d_ws, size_t ws_size,
                              hipStream_t stream) {
    const float* x     = (const float*)d_in[0];
    const float* wq    = (const float*)d_in[1];
    const float* bq    = (const float*)d_in[2];
    const float* wk    = (const float*)d_in[3];
    const float* bk    = (const float*)d_in[4];
    const float* wv    = (const float*)d_in[5];
    const float* bv    = (const float*)d_in[6];
    const float* gamma = (const float*)d_in[7];
    float* out  = (float*)d_out;
    float* amap = out + (size_t)B * C * NN;

    const size_t WS_NEED = (size_t)26 << 20;
    if (ws_size < WS_NEED) {
        k_sentinel<<<dim3(1), dim3(1), 0, stream>>>(out, 8.0e7f);
        return;
    }
    if (n_in < 8 || in_sizes[0] != B * C * NN || in_sizes[1] != 32 * C ||
        in_sizes[2] != 32 || in_sizes[3] != 32 * C || in_sizes[4] != 32 ||
        in_sizes[5] != C * C || in_sizes[6] != C || in_sizes[7] != 1) {
        k_sentinel<<<dim3(1), dim3(1), 0, stream>>>(out, 9.0e7f);
        return;
    }

    unsigned char* ws = (unsigned char*)d_ws;
    u16* qh   = (u16*)(ws);
    u16* ql   = (u16*)(ws + ((size_t)2 << 20));
    u16* kh   = (u16*)(ws + ((size_t)4 << 20));
    u16* kl   = (u16*)(ws + ((size_t)6 << 20));
    u16* vbf  = (u16*)(ws + ((size_t)8 << 20));
    float* zinv = (float*)(ws + ((size_t)24 << 20));
    u16* wvb  = (u16*)(ws + ((size_t)25 << 20));
    u16* wqh  = (u16*)(ws + ((size_t)25 << 20) + (128 << 10));
    u16* wql  = (u16*)(ws + ((size_t)25 << 20) + (144 << 10));
    u16* wkh  = (u16*)(ws + ((size_t)25 << 20) + (160 << 10));
    u16* wkl  = (u16*)(ws + ((size_t)25 << 20) + (176 << 10));

    k_cast<<<dim3(320), dim3(256), 0, stream>>>(wv, wq, wk, wvb, wqh, wql, wkh, wkl);
    k_proj<<<dim3(8, 64), dim3(256), 0, stream>>>(x, wvb, bv, wqh, wql, bq, wkh, wkl, bk,
                                                  vbf, qh, ql, kh, kl);
    k_zsum<<<dim3(8, 64), dim3(256), 0, stream>>>(qh, ql, kh, kl, zinv);
    k_attn2<<<dim3(8, 64), dim3(256), 0, stream>>>(x, qh, ql, kh, kl, vbf, zinv, gamma, out, amap);
}

// Round 18
// 268.827 us; speedup vs baseline: 1.0487x; 1.0487x over previous
//
#include <hip/hip_runtime.h>

#define B 8
#define C 256
#define NN 4096

typedef float f32x4 __attribute__((ext_vector_type(4)));
typedef short s16x8 __attribute__((ext_vector_type(8)));
typedef unsigned short u16;
typedef unsigned int u32;

__device__ __forceinline__ u16 f2bf(float f) {
    u32 u = __builtin_bit_cast(u32, f);
    u32 r = (u + 0x7fffu + ((u >> 16) & 1u)) >> 16;
    return (u16)r;
}
__device__ __forceinline__ float bf2f(u16 h) {
    u32 u = ((u32)h) << 16;
    return __builtin_bit_cast(float, u);
}

// LDS-only barrier: waits lgkmcnt(0) (LDS) but NOT vmcnt (outstanding global
// stores keep draining in background). FUSED into one asm block so no LDS op
// can ever be scheduled between the waitcnt and the barrier (round-13 race).
__device__ __forceinline__ void bar_lds() {
    asm volatile("s_waitcnt lgkmcnt(0)\n\ts_barrier" ::: "memory");
}

#define MFMA(a, b, c) __builtin_amdgcn_mfma_f32_16x16x32_bf16((a), (b), (c), 0, 0, 0)

// Validated convention (round-3 k_st1/k_st2 on-device): afrag@(lan,g)=A[lan][g*8+e],
// bfrag@(lan,g)=B[lan][g*8+e], D[r]@(lan,g) = sum A[g*4+r][:]*B[lan][:].
// Transposed-score: A = Q (rows n), B = K (rows m) -> lane holds m = mbase+lan,
// 4 consecutive n = g*4+r. Used IDENTICALLY in k_zsum and k_attn2.
__device__ __forceinline__ f32x4 score_mfma_t(s16x8 aqh, s16x8 aql, s16x8 bkh, s16x8 bkl) {
    f32x4 s = {0.f, 0.f, 0.f, 0.f};
    s = MFMA(aqh, bkl, s);
    s = MFMA(aql, bkh, s);
    s = MFMA(aqh, bkh, s);
    return s;
}

__global__ void k_sentinel(float* __restrict__ out, float v) { out[0] = v; }

// ---- weight casts into FRAGMENT-MAJOR layout: [(es*8+ck)*4+g][lan][8] ----
// Dest index i encodes (es,ck,g,lan,e); source is row-major weight [d][c].
// Makes every MFMA A-operand load in k_proj one contiguous 1KB wave-load
// (was: 64x16B gather at 512B stride).
__global__ void k_cast(const float* __restrict__ wv, const float* __restrict__ wq,
                       const float* __restrict__ wk, u16* __restrict__ wvb,
                       u16* __restrict__ wqh, u16* __restrict__ wql,
                       u16* __restrict__ wkh, u16* __restrict__ wkl) {
    int i = blockIdx.x * 256 + threadIdx.x; // 320 blocks -> 81920
    if (i < 65536) {
        int e = i & 7, lan = (i >> 3) & 15, g = (i >> 7) & 3, ck = (i >> 9) & 7, es = i >> 12;
        wvb[i] = f2bf(wv[(es * 16 + lan) * 256 + ck * 32 + g * 8 + e]);
    } else if (i < 73728) {
        int j = i - 65536;
        int e = j & 7, lan = (j >> 3) & 15, g = (j >> 7) & 3, ck = (j >> 9) & 7, es = j >> 12;
        float v = wq[(es * 16 + lan) * 256 + ck * 32 + g * 8 + e];
        u16 h = f2bf(v); wqh[j] = h; wql[j] = f2bf(v - bf2f(h));
    } else {
        int j = i - 73728;
        int e = j & 7, lan = (j >> 3) & 15, g = (j >> 7) & 3, ck = (j >> 9) & 7, es = j >> 12;
        float v = wk[(es * 16 + lan) * 256 + ck * 32 + g * 8 + e];
        u16 h = f2bf(v); wkh[j] = h; wkl[j] = f2bf(v - bf2f(h));
    }
}

// ------- fused q/k/v projection: one xT staging (hi/lo), MFMA for all three -------
__global__ __launch_bounds__(256) void k_proj(
    const float* __restrict__ x,
    const u16* __restrict__ wvb, const float* __restrict__ bv,
    const u16* __restrict__ wqh, const u16* __restrict__ wql, const float* __restrict__ bq,
    const u16* __restrict__ wkh, const u16* __restrict__ wkl, const float* __restrict__ bk,
    u16* __restrict__ vbf,
    u16* __restrict__ qh, u16* __restrict__ ql, u16* __restrict__ kh, u16* __restrict__ kl)
{
    __shared__ u16 smh[64 * 264]; // xT hi [64 n][264 c-pad]
    __shared__ u16 sml[64 * 264]; // xT lo; reused later as sqk [64 n][136]
    int t = threadIdx.x;
    int w = t >> 6, l = t & 63;
    int lan = l & 15, g = l >> 4;
    int b = blockIdx.x, nblk = blockIdx.y;
    int n0 = nblk * 64;
#pragma unroll
    for (int p = 0; p < 16; p++) {
        int flat4 = t + p * 256;
        int c = flat4 >> 4, n4 = (flat4 & 15) * 4;
        float4 xv = *(const float4*)&x[((size_t)b * C + c) * NN + n0 + n4];
        float vv[4] = {xv.x, xv.y, xv.z, xv.w};
#pragma unroll
        for (int j = 0; j < 4; j++) {
            u16 h = f2bf(vv[j]);
            smh[(n4 + j) * 264 + c] = h;
            sml[(n4 + j) * 264 + c] = f2bf(vv[j] - bf2f(h));
        }
    }
    __syncthreads();
    f32x4 accv[16];
    f32x4 accq[2], acck[2];
#pragma unroll
    for (int es = 0; es < 16; es++) accv[es] = {0.f, 0.f, 0.f, 0.f};
#pragma unroll
    for (int es = 0; es < 2; es++) { accq[es] = {0.f, 0.f, 0.f, 0.f}; acck[es] = {0.f, 0.f, 0.f, 0.f}; }
    int nrow = w * 16 + lan;
    for (int ck = 0; ck < 8; ck++) {
        int c0 = ck * 32 + g * 8;
        int fb = ((ck * 4 + g) * 16 + lan) * 8; // fragment base (es stride 4096)
        s16x8 bh = *(const s16x8*)&smh[nrow * 264 + c0];
        s16x8 bl = *(const s16x8*)&sml[nrow * 264 + c0];
#pragma unroll
        for (int es = 0; es < 16; es++) {
            s16x8 afrag = *(const s16x8*)&wvb[es * 4096 + fb];
            accv[es] = MFMA(afrag, bh, accv[es]);
        }
#pragma unroll
        for (int es = 0; es < 2; es++) {
            s16x8 ah = *(const s16x8*)&wqh[es * 4096 + fb];
            s16x8 al = *(const s16x8*)&wql[es * 4096 + fb];
            accq[es] = MFMA(ah, bl, accq[es]);
            accq[es] = MFMA(al, bh, accq[es]);
            accq[es] = MFMA(ah, bh, accq[es]);
            ah = *(const s16x8*)&wkh[es * 4096 + fb];
            al = *(const s16x8*)&wkl[es * 4096 + fb];
            acck[es] = MFMA(ah, bl, acck[es]);
            acck[es] = MFMA(al, bh, acck[es]);
            acck[es] = MFMA(ah, bh, acck[es]);
        }
    }
    // V writeout
    int ncol = n0 + w * 16 + lan;
#pragma unroll
    for (int es = 0; es < 16; es++)
#pragma unroll
        for (int r = 0; r < 4; r++) {
            int e = es * 16 + g * 4 + r;
            vbf[((size_t)b * C + e) * NN + ncol] = f2bf(accv[es][r] + bv[e]);
        }
    // q/k: split hi/lo in-register, transpose via LDS (reuse sml as sqk[64][136]).
    bar_lds(); // don't drain the V stores above
    u16* sqk = sml;
    int nloc = w * 16 + lan;
#pragma unroll
    for (int es = 0; es < 2; es++)
#pragma unroll
        for (int r = 0; r < 4; r++) {
            int d = es * 16 + g * 4 + r;
            float qv = accq[es][r] + bq[d];
            float kv = acck[es][r] + bk[d];
            u16 qhi = f2bf(qv); u16 qlo = f2bf(qv - bf2f(qhi));
            u16 khi = f2bf(kv); u16 klo = f2bf(kv - bf2f(khi));
            sqk[nloc * 136 + 0 * 32 + d] = qhi;
            sqk[nloc * 136 + 1 * 32 + d] = qlo;
            sqk[nloc * 136 + 2 * 32 + d] = khi;
            sqk[nloc * 136 + 3 * 32 + d] = klo;
        }
    bar_lds();
    {
        int n = t >> 2, arr = t & 3;
        const u16* src = &sqk[n * 136 + arr * 32];
        u16* dst = (arr == 0 ? qh : arr == 1 ? ql : arr == 2 ? kh : kl) + ((size_t)b * NN + n0 + n) * 32;
        uint4 v0 = *(const uint4*)&src[0];
        uint4 v1 = *(const uint4*)&src[8];
        uint4 v2 = *(const uint4*)&src[16];
        uint4 v3 = *(const uint4*)&src[24];
        *(uint4*)&dst[0]  = v0;
        *(uint4*)&dst[8]  = v1;
        *(uint4*)&dst[16] = v2;
        *(uint4*)&dst[24] = v3;
    }
}

// ------- phase 1: Z sums, transposed scores (lane-local m rows) -------
__global__ __launch_bounds__(256) void k_zsum(
    const u16* __restrict__ qh, const u16* __restrict__ ql,
    const u16* __restrict__ kh, const u16* __restrict__ kl,
    float* __restrict__ zinv)
{
    __shared__ float lZ[4][64];
    int t = threadIdx.x;
    int w = t >> 6, l = t & 63;
    int lan = l & 15, g = l >> 4;
    int b = blockIdx.x, mblk = blockIdx.y;
    int m0 = mblk * 64;

    s16x8 bkh[4], bkl[4];
#pragma unroll
    for (int ms = 0; ms < 4; ms++) {
        size_t ko = ((size_t)b * NN + m0 + ms * 16 + lan) * 32 + g * 8;
        bkh[ms] = *(const s16x8*)&kh[ko];
        bkl[ms] = *(const s16x8*)&kl[ko];
    }
    float zacc[4] = {0.f, 0.f, 0.f, 0.f};
    for (int ci = 0; ci < 64; ci++) {
        int nt = ci * 4 + w;
        size_t qo = ((size_t)b * NN + nt * 16 + lan) * 32 + g * 8;
        s16x8 aqh = *(const s16x8*)&qh[qo];
        s16x8 aql = *(const s16x8*)&ql[qo];
#pragma unroll
        for (int ms = 0; ms < 4; ms++) {
            f32x4 s = score_mfma_t(aqh, aql, bkh[ms], bkl[ms]);
            zacc[ms] += __expf(s[0]) + __expf(s[1]) + __expf(s[2]) + __expf(s[3]);
        }
    }
#pragma unroll
    for (int ms = 0; ms < 4; ms++) {
        float v = zacc[ms];
        v += __shfl_xor(v, 16);
        v += __shfl_xor(v, 32);
        zacc[ms] = v;
    }
    if (g == 0) {
#pragma unroll
        for (int ms = 0; ms < 4; ms++) lZ[w][ms * 16 + lan] = zacc[ms];
    }
    __syncthreads();
    if (t < 64) {
        float Z = lZ[0][t] + lZ[1][t] + lZ[2][t] + lZ[3][t];
        zinv[(size_t)b * NN + m0 + t] = 1.0f / Z;
    }
}

// ------- phase 2: V in LDS (T14), bf16 A tile, lgkm-only fused barriers -------
__global__ __launch_bounds__(256) void k_attn2(
    const float* __restrict__ x,
    const u16* __restrict__ qh, const u16* __restrict__ ql,
    const u16* __restrict__ kh, const u16* __restrict__ kl,
    const u16* __restrict__ vbf, const float* __restrict__ zinv,
    const float* __restrict__ gamma,
    float* __restrict__ out, float* __restrict__ amap)
{
    __shared__ u16 smv[16384];   // V tile [256 c][64 m], chunk-XOR-swizzled (32KB)
    __shared__ u16 mn[64 * 68];  // A tile [64 m][68-pad n] bf16 (8.7KB)
    int t = threadIdx.x;
    int w = t >> 6, l = t & 63;
    int lan = l & 15, g = l >> 4;
    int b = blockIdx.x, nblk = blockIdx.y;
    int n0 = nblk * 64;
    int nw = n0 + w * 16;

    size_t qo = ((size_t)b * NN + nw + lan) * 32 + g * 8;
    s16x8 aqh = *(const s16x8*)&qh[qo];
    s16x8 aql = *(const s16x8*)&ql[qo];

    f32x4 acc[16];
#pragma unroll
    for (int cs = 0; cs < 16; cs++) acc[cs] = {0.f, 0.f, 0.f, 0.f};
    const u16* vb = vbf + (size_t)b * C * NN;
    const float* ziv = zinv + (size_t)b * NN;
    float* amp = amap + (size_t)b * NN * NN;

    // prologue: stage V tile 0
    s16x8 vreg[8];
#pragma unroll
    for (int p = 0; p < 8; p++) {
        int f8 = t + p * 256; int c = f8 >> 3, j = f8 & 7;
        vreg[p] = *(const s16x8*)&vb[(size_t)c * NN + j * 8];
    }
#pragma unroll
    for (int p = 0; p < 8; p++) {
        int f8 = t + p * 256; int c = f8 >> 3, j = f8 & 7;
        *(s16x8*)&smv[c * 64 + ((j ^ (c & 7)) * 8)] = vreg[p];
    }
    bar_lds();

    for (int mstep = 0; mstep < 64; mstep++) {
        int m0 = mstep * 64;
        // scores: lane owns m = m0+ms*16+lan, n = nw+g*4+r -> mn (bf16)
#pragma unroll
        for (int ms = 0; ms < 4; ms++) {
            size_t ko = ((size_t)b * NN + m0 + ms * 16 + lan) * 32 + g * 8;
            s16x8 fkh = *(const s16x8*)&kh[ko];
            s16x8 fkl = *(const s16x8*)&kl[ko];
            f32x4 s = score_mfma_t(aqh, aql, fkh, fkl);
            float zi = ziv[m0 + ms * 16 + lan];
            uint2 pk;
            pk.x = (u32)f2bf(__expf(s[0]) * zi) | ((u32)f2bf(__expf(s[1]) * zi) << 16);
            pk.y = (u32)f2bf(__expf(s[2]) * zi) | ((u32)f2bf(__expf(s[3]) * zi) << 16);
            *(uint2*)&mn[(ms * 16 + lan) * 68 + w * 16 + g * 4] = pk;
        }
        bar_lds(); // bar1: mn visible to all waves (global stores NOT drained)
        // T14: issue next V tile's loads BEFORE the stores
        if (mstep < 63) {
#pragma unroll
            for (int p = 0; p < 8; p++) {
                int f8 = t + p * 256; int c = f8 >> 3, j = f8 & 7;
                vreg[p] = *(const s16x8*)&vb[(size_t)c * NN + m0 + 64 + j * 8];
            }
        }
        // amap stores: 16 lanes x 16B = 256B fully contiguous per row; nontemporal
#pragma unroll
        for (int p = 0; p < 4; p++) {
            int mm = p * 16 + (t >> 4);
            int c4 = (t & 15) * 4;
            uint2 pk = *(const uint2*)&mn[mm * 68 + c4];
            f32x4 v;
            v[0] = bf2f((u16)(pk.x & 0xffff)); v[1] = bf2f((u16)(pk.x >> 16));
            v[2] = bf2f((u16)(pk.y & 0xffff)); v[3] = bf2f((u16)(pk.y >> 16));
            __builtin_nontemporal_store(v, (f32x4*)&amp[(size_t)(m0 + mm) * NN + n0 + c4]);
        }
        // PV: acc[cs] (c = cs*16+g*4+r, n = nw+lan) += V[c][m] * A[m][n]
#pragma unroll
        for (int ks = 0; ks < 2; ks++) {
            s16x8 bfrag;
#pragma unroll
            for (int e = 0; e < 8; e++)
                bfrag[e] = (short)mn[(ks * 32 + g * 8 + e) * 68 + w * 16 + lan];
#pragma unroll
            for (int cs = 0; cs < 16; cs++) {
                int row = cs * 16 + lan;
                s16x8 afrag = *(const s16x8*)&smv[row * 64 + (((ks * 4 + g) ^ (lan & 7)) * 8)];
                acc[cs] = MFMA(afrag, bfrag, acc[cs]);
            }
        }
        bar_lds(); // bar2: all reads of mn & smv complete
        if (mstep < 63) {
#pragma unroll
            for (int p = 0; p < 8; p++) {
                int f8 = t + p * 256; int c = f8 >> 3, j = f8 & 7;
                *(s16x8*)&smv[c * 64 + ((j ^ (c & 7)) * 8)] = vreg[p];
            }
        }
    }
    float gm = gamma[0];
    int ncol = nw + lan;
#pragma unroll
    for (int cs = 0; cs < 16; cs++)
#pragma unroll
        for (int r = 0; r < 4; r++) {
            int c = cs * 16 + g * 4 + r;
            size_t oi = ((size_t)b * C + c) * NN + ncol;
            out[oi] = gm * acc[cs][r] + x[oi];
        }
}

extern "C" void kernel_launch(void* const* d_in, const int* in_sizes, int n_in,
                              void* d_out, int out_size, void* d_ws, size_t ws_size,
                              hipStream_t stream) {
    const float* x     = (const float*)d_in[0];
    const float* wq    = (const float*)d_in[1];
    const float* bq    = (const float*)d_in[2];
    const float* wk    = (const float*)d_in[3];
    const float* bk    = (const float*)d_in[4];
    const float* wv    = (const float*)d_in[5];
    const float* bv    = (const float*)d_in[6];
    const float* gamma = (const float*)d_in[7];
    float* out  = (float*)d_out;
    float* amap = out + (size_t)B * C * NN;

    const size_t WS_NEED = (size_t)26 << 20;
    if (ws_size < WS_NEED) {
        k_sentinel<<<dim3(1), dim3(1), 0, stream>>>(out, 8.0e7f);
        return;
    }
    if (n_in < 8 || in_sizes[0] != B * C * NN || in_sizes[1] != 32 * C ||
        in_sizes[2] != 32 || in_sizes[3] != 32 * C || in_sizes[4] != 32 ||
        in_sizes[5] != C * C || in_sizes[6] != C || in_sizes[7] != 1) {
        k_sentinel<<<dim3(1), dim3(1), 0, stream>>>(out, 9.0e7f);
        return;
    }

    unsigned char* ws = (unsigned char*)d_ws;
    u16* qh   = (u16*)(ws);
    u16* ql   = (u16*)(ws + ((size_t)2 << 20));
    u16* kh   = (u16*)(ws + ((size_t)4 << 20));
    u16* kl   = (u16*)(ws + ((size_t)6 << 20));
    u16* vbf  = (u16*)(ws + ((size_t)8 << 20));
    float* zinv = (float*)(ws + ((size_t)24 << 20));
    u16* wvb  = (u16*)(ws + ((size_t)25 << 20));
    u16* wqh  = (u16*)(ws + ((size_t)25 << 20) + (128 << 10));
    u16* wql  = (u16*)(ws + ((size_t)25 << 20) + (144 << 10));
    u16* wkh  = (u16*)(ws + ((size_t)25 << 20) + (160 << 10));
    u16* wkl  = (u16*)(ws + ((size_t)25 << 20) + (176 << 10));

    k_cast<<<dim3(320), dim3(256), 0, stream>>>(wv, wq, wk, wvb, wqh, wql, wkh, wkl);
    k_proj<<<dim3(8, 64), dim3(256), 0, stream>>>(x, wvb, bv, wqh, wql, bq, wkh, wkl, bk,
                                                  vbf, qh, ql, kh, kl);
    k_zsum<<<dim3(8, 64), dim3(256), 0, stream>>>(qh, ql, kh, kl, zinv);
    k_attn2<<<dim3(8, 64), dim3(256), 0, stream>>>(x, qh, ql, kh, kl, vbf, zinv, gamma, out, amap);
}